// Round 7
// baseline (349.034 us; speedup 1.0000x reference)
//
#include <hip/hip_runtime.h>
#include <math.h>

// Problem constants (B, C, H, W) = (4, 128, 192, 192)
#define BB 4
#define CC 128
#define HH 192
#define WW 192
#define HWSZ (HH * WW)          // 36864
#define NPIX (BB * HWSZ)        // 147456
#define PD 194                  // padded H/W for bf16 activation buffers

typedef __attribute__((ext_vector_type(8))) short short8;
typedef __attribute__((ext_vector_type(4))) short short4v;
typedef __attribute__((ext_vector_type(16))) float float16v;

// fp32 -> bf16, round-to-nearest-even
__device__ __forceinline__ short f2bf(float f) {
    unsigned u = __float_as_uint(f);
    u += 0x7FFF + ((u >> 16) & 1);
    return (short)(u >> 16);
}
__device__ __forceinline__ float bf2f(short s) {
    return __uint_as_float(((unsigned)(unsigned short)s) << 16);
}

// ---------------------------------------------------------------------------
// Weight prep: w[co][cin][ky][kx] fp32 ->
//   wp[sl][ck][tt][tap3][kh][hi][co][ci8] bf16
//   cin = ck*32 + (kh*2+hi)*8 + ci8, tap = tt*3 + tap3
// Matches the 32x32x16 MFMA A-operand: lane l reads co=l&31(+32*mi),
// k-octet = (l>>5) within k-half kh -> contiguous 16B per lane,
// conflict-free ds_read_b128.
// ---------------------------------------------------------------------------
__global__ void prep_w_kernel(const float* __restrict__ w,
                              short* __restrict__ wp,
                              int CIN, int COUT, int NSLICE, int total) {
    int idx = blockIdx.x * blockDim.x + threadIdx.x;
    if (idx >= total) return;
    int CKN = CIN / 32;
    int ci8 = idx & 7;
    int t   = idx >> 3;
    int co  = t % COUT;  t /= COUT;
    int hi  = t % 2;     t /= 2;
    int kh  = t % 2;     t /= 2;
    int tap3 = t % 3;    t /= 3;
    int tt  = t % 3;     t /= 3;
    int ck  = t % CKN;
    int sl  = t / CKN;
    int cin = ck * 32 + (kh * 2 + hi) * 8 + ci8;
    int tap = tt * 3 + tap3;
    int co_g = sl * COUT + co;
    wp[idx] = f2bf(w[(co_g * CIN + cin) * 9 + tap]);
}

// ---------------------------------------------------------------------------
// Zero the borders of the three padded bf16 activation buffers.
// ---------------------------------------------------------------------------
__global__ void zero_pads_kernel(short* __restrict__ p0,
                                 short* __restrict__ p1,
                                 short* __restrict__ p2) {
    int idx = blockIdx.x * blockDim.x + threadIdx.x;
    if (idx >= 3 * 64 * 772) return;
    int e   = idx % 772;
    int bc  = (idx / 772) % 64;
    int buf = idx / (772 * 64);
    short* base = (buf == 0) ? p0 : (buf == 1) ? p1 : p2;
    int row, col;
    if (e < 194)      { row = 0;   col = e; }
    else if (e < 388) { row = 193; col = e - 194; }
    else { int e2 = e - 388; row = 1 + (e2 >> 1); col = (e2 & 1) * 193; }
    short8 z = {0, 0, 0, 0, 0, 0, 0, 0};
    *(short8*)&base[(((size_t)bc * PD + row) * PD + col) * 8] = z;
}

// ---------------------------------------------------------------------------
// x fp32 NCHW -> padded bf16 8c-blocked [b][cg][h+1][w+1][8]
// ---------------------------------------------------------------------------
__global__ void x_prep_kernel(const float* __restrict__ x,
                              short* __restrict__ xp) {
    int idx = blockIdx.x * blockDim.x + threadIdx.x;
    if (idx >= BB * 16 * HWSZ) return;
    int w  = idx % WW;
    int h  = (idx / WW) % HH;
    int cg = (idx / HWSZ) % 16;
    int b  = idx / (HWSZ * 16);
    const float* p = x + ((size_t)(b * CC + cg * 8) * HH + h) * WW + w;
    short8 pk;
#pragma unroll
    for (int j = 0; j < 8; ++j) pk[j] = f2bf(p[(size_t)j * HWSZ]);
    *(short8*)&xp[((((size_t)b * 16 + cg) * PD + h + 1) * PD + (w + 1)) * 8] = pk;
}

// ---------------------------------------------------------------------------
// Implicit-GEMM 3x3 conv, bf16 MFMA **32x32x16**, fp32 accumulate.
// 6 waves x 384 thr: each wave owns 32 pixels x full COUT slice (WM m-tiles
//   of 32 couts). No B duplication; half the MFMA instructions of the
//   16x16x32 version at a 15% higher ceiling.
// A (weights): 3-tap sub-chunks double-buffered via global_load_lds; rolling
//   2-deep A-fragment buffer (intra-wave LDS||MFMA overlap). Counted
//   vmcnt(4) at stage boundaries drains only the staging DMAs (T4).
// B (activations): 6 per-lane row pointers (3 dy x 2 k-half) + immediate
//   offsets; ring-3, distance-2 prefetch.
// Block -> (b,h,sl) chunked XCD swizzle. T5 setprio on the MFMA cluster.
// ---------------------------------------------------------------------------
template <int CIN, int COUT, int NSLICE, int WM, bool RELU, bool OUT_F32>
__global__ __launch_bounds__(384, 3)
void conv3x3_wlds(const short* __restrict__ in,
                  const short* __restrict__ wp,   // [sl][stage][tap3][kh][hi][co][8]
                  const float* __restrict__ bias,
                  void* __restrict__ outv) {
    constexpr int CKN   = CIN / 32;
    constexpr int CG_IN = CIN / 8;
    constexpr int COUT_TOT = COUT * NSLICE;
    constexpr int CGO   = COUT_TOT / 8;
    constexpr int NT    = 384;
    constexpr int SUB   = 3 * 2 * 2 * COUT * 8;  // shorts per 3-tap sub-chunk
    constexpr int SUBB  = SUB * 2;               // bytes
    constexpr int A_T3  = 4 * COUT * 16;         // tap3 stride (bytes)
    constexpr int A_KH  = 2 * COUT * 16;         // k-half stride (bytes)
    constexpr int NS    = CKN * 3;               // number of stages
    constexpr int KTMAX = CKN * 9;
    constexpr int CKB   = PD * PD * 64;          // B row-base advance per ck (bytes)
    constexpr int WPSL  = NS * SUB;              // shorts per cout-slice of wp
    constexpr int NWG   = BB * HH * NSLICE;      // total workgroups
    static_assert(WM * 32 == COUT, "M tiling");
    static_assert((SUB / 8) % NT == 0, "DMA units divide thread count");

    __shared__ __align__(16) short s_w[2 * SUB];

    const int tid  = threadIdx.x;
    // ---- chunked XCD swizzle over (b, h, sl) work ids ----
    const int lin  = blockIdx.y * (HH * NSLICE) + blockIdx.x;
    const int L    = (lin & 7) * (NWG >> 3) + (lin >> 3);
    const int sl   = L % NSLICE;
    const int h    = (L / NSLICE) % HH;
    const int b    = L / (NSLICE * HH);
    const int lane = tid & 63;
    const int wv   = tid >> 6;               // 0..5, pixel group
    const int l31  = lane & 31;
    const int hi   = lane >> 5;              // k-octet within k-half

    float16v acc[WM];
#pragma unroll
    for (int mi = 0; mi < WM; ++mi)
#pragma unroll
        for (int e = 0; e < 16; ++e) acc[mi][e] = 0.f;

    short8 Aa[2][2][WM];                     // [buf][kh][mi]
    short8 Bb[3][2];                         // [ring t3][kh]

    // ---- B row-base pointers: 3 dy x 2 k-half, per-lane (cg = kh*2+hi) ----
    const int colb = (wv * 32 + l31) * 16;   // pixel byte offset
    const char* r00 = (const char*)in +
        ((((size_t)b * CG_IN + hi) * PD + h) * PD) * 16 + colb;
    const char* r01 = r00 + (size_t)2 * PD * PD * 16;   // kh=1 -> +2 cgs
    const char* r10 = r00 + PD * 16;
    const char* r11 = r01 + PD * 16;
    const char* r20 = r00 + 2 * PD * 16;
    const char* r21 = r01 + 2 * PD * 16;

    // ---- A LDS base (per-lane) ----
    const char* aBase = (const char*)&s_w[0] + (hi * COUT + l31) * 16;

    // B load: dy/dx compile-time after unroll -> pure immediate-offset loads
    auto loadB = [&](int dy, int dx, int slot) {
        const char* p0 = (dy == 0) ? r00 : (dy == 1) ? r10 : r20;
        const char* p1 = (dy == 0) ? r01 : (dy == 1) ? r11 : r21;
        Bb[slot][0] = *(const short8*)(p0 + dx * 16);
        Bb[slot][1] = *(const short8*)(p1 + dx * 16);
    };

    // weight staging DMA (pure width-16), advances source/parity
    const short* wsrc = wp + (size_t)sl * WPSL;
    int wpar = 0;
    auto stageIssue = [&]() {
        constexpr int UNITS = SUB / 8;               // 16B units
        short* dstb = &s_w[wpar * SUB];
#pragma unroll
        for (int u = 0; u < UNITS / NT; ++u) {
            int i = tid + u * NT;
            __builtin_amdgcn_global_load_lds(
                (const __attribute__((address_space(1))) void*)&wsrc[i * 8],
                (__attribute__((address_space(3))) void*)&dstb[i * 8], 16, 0, 0);
        }
        // pin later VMEM ops after the DMA issue (vmcnt count depends on it)
        asm volatile("" ::: "memory");
        wsrc += SUB;
        wpar ^= 1;
    };

    // ---- prologue: stage 0 weights, fill 2 B ring slots (taps 0,1) ----
    stageIssue();
    loadB(0, 0, 0);
    loadB(0, 1, 1);
    // outstanding: {<=2 DMA (oldest), 4 B} -> vmcnt(4) drains exactly the DMAs
    asm volatile("s_waitcnt vmcnt(4)" ::: "memory");
    __builtin_amdgcn_s_barrier();
    asm volatile("" ::: "memory");

    int par = 0;
    for (int ck = 0; ck < CKN; ++ck) {
#pragma unroll
        for (int tt = 0; tt < 3; ++tt) {
            const int s = ck * 3 + tt;
            const bool notLast = (s + 1 < NS);
            if (notLast) stageIssue();
            const char* aP = aBase + (par ? SUBB : 0);
            // A fragments of tap3=0 (rolling buffer 0)
#pragma unroll
            for (int kh = 0; kh < 2; ++kh)
#pragma unroll
                for (int mi = 0; mi < WM; ++mi)
                    Aa[0][kh][mi] = *(const short8*)
                        (aP + kh * A_KH + mi * 512);
#pragma unroll
            for (int t3 = 0; t3 < 3; ++t3) {
                if (t3 < 2) {
#pragma unroll
                    for (int kh = 0; kh < 2; ++kh)
#pragma unroll
                        for (int mi = 0; mi < WM; ++mi)
                            Aa[(t3 + 1) & 1][kh][mi] = *(const short8*)
                                (aP + (t3 + 1) * A_T3 + kh * A_KH + mi * 512);
                }
                const int kt = s * 3 + t3;
                if (kt + 2 < KTMAX) {
                    const int tp = (tt * 3 + t3 + 2) % 9;   // compile-time
                    loadB(tp / 3, tp % 3, (t3 + 2) % 3);
                }
                __builtin_amdgcn_s_setprio(1);
#pragma unroll
                for (int mi = 0; mi < WM; ++mi)
#pragma unroll
                    for (int kh = 0; kh < 2; ++kh)
                        acc[mi] = __builtin_amdgcn_mfma_f32_32x32x16_bf16(
                            Aa[t3 & 1][kh][mi], Bb[t3][kh], acc[mi], 0, 0, 0);
                __builtin_amdgcn_s_setprio(0);
                // advance B row bases AFTER tap8 prefetch (tt=2,t3=0),
                // BEFORE the cross-ck prefetches at (2,1)/(2,2)
                if (tt == 2 && t3 == 0) {
                    r00 += CKB; r01 += CKB; r10 += CKB;
                    r11 += CKB; r20 += CKB; r21 += CKB;
                }
            }
            if (notLast) {
                // outstanding: {<=2 DMA(s+1) oldest, 4 B newest} -> drain DMAs
                asm volatile("s_waitcnt vmcnt(4)" ::: "memory");
                __builtin_amdgcn_s_barrier();
                asm volatile("" ::: "memory");
                par ^= 1;
            }
        }
    }

    // ---- epilogue: C layout col(pixel)=lane&31, row(co)=8q+4hi+e ----
    const int px = wv * 32 + l31;
    if (OUT_F32) {
        float* out = (float*)outv;
#pragma unroll
        for (int mi = 0; mi < WM; ++mi) {
#pragma unroll
            for (int q = 0; q < 4; ++q) {
                int co0 = sl * COUT + mi * 32 + q * 8 + hi * 4;
#pragma unroll
                for (int e = 0; e < 4; ++e) {
                    int co = co0 + e;
                    float v = acc[mi][q * 4 + e] + bias[co];
                    if (RELU) v = fmaxf(v, 0.f);
                    out[((size_t)(b * COUT_TOT + co) * HH + h) * WW + px] = v;
                }
            }
        }
    } else {
        short* out = (short*)outv;
#pragma unroll
        for (int mi = 0; mi < WM; ++mi) {
#pragma unroll
            for (int q = 0; q < 4; ++q) {
                int co0 = sl * COUT + mi * 32 + q * 8 + hi * 4;
                int cg  = co0 >> 3;
                int sub = co0 & 7;                   // 0 or 4
                short4v pk;
#pragma unroll
                for (int e = 0; e < 4; ++e) {
                    float v = acc[mi][q * 4 + e] + bias[co0 + e];
                    if (RELU) v = fmaxf(v, 0.f);
                    pk[e] = f2bf(v);
                }
                *(short4v*)&out[((((size_t)b * CGO + cg) * PD + (h + 1)) * PD +
                                 (px + 1)) * 8 + sub] = pk;
            }
        }
    }
}

// ---------------------------------------------------------------------------
// conv1x1 (32 -> 9 logits) + softmax; reads bf16 8c-blocked padded t2.
// ---------------------------------------------------------------------------
__global__ void conv1x1_softmax_kernel(const short* __restrict__ t2,
                                       const float* __restrict__ w3,   // (9,32)
                                       const float* __restrict__ b3,
                                       float* __restrict__ kern) {     // (B,9,H,W)
    __shared__ float sw[9 * 32];
    __shared__ float sb[9];
    for (int i = threadIdx.x; i < 9 * 32; i += blockDim.x) sw[i] = w3[i];
    if (threadIdx.x < 9) sb[threadIdx.x] = b3[threadIdx.x];
    __syncthreads();

    int idx = blockIdx.x * blockDim.x + threadIdx.x;
    if (idx >= NPIX) return;
    int b = idx / HWSZ;
    int p = idx % HWSZ;
    int h = p / WW, w = p % WW;

    float v[32];
#pragma unroll
    for (int cg = 0; cg < 4; ++cg) {
        short8 pk = *(const short8*)
            &t2[((((size_t)b * 4 + cg) * PD + h + 1) * PD + (w + 1)) * 8];
#pragma unroll
        for (int j = 0; j < 8; ++j) v[cg * 8 + j] = bf2f(pk[j]);
    }

    float lg[9];
    float m = -1e30f;
#pragma unroll
    for (int t = 0; t < 9; ++t) {
        float s = sb[t];
#pragma unroll
        for (int c = 0; c < 32; ++c) s = fmaf(sw[t * 32 + c], v[c], s);
        lg[t] = s;
        m = fmaxf(m, s);
    }
    float sum = 0.f;
#pragma unroll
    for (int t = 0; t < 9; ++t) {
        lg[t] = __expf(lg[t] - m);
        sum += lg[t];
    }
    float inv = 1.f / sum;
#pragma unroll
    for (int t = 0; t < 9; ++t)
        kern[((size_t)(b * 9 + t)) * HWSZ + p] = lg[t] * inv;
}

// ---------------------------------------------------------------------------
// Adaptive 3x3 filter apply: fp32 x (exact) * fp32 kernel -> bf16 8c t3.
// ---------------------------------------------------------------------------
__global__ void deblur_kernel(const float* __restrict__ x,
                              const float* __restrict__ kern,
                              short* __restrict__ t3) {
    int idx = blockIdx.x * blockDim.x + threadIdx.x;
    if (idx >= BB * 16 * HWSZ) return;
    int w  = idx % WW;
    int h  = (idx / WW) % HH;
    int cg = (idx / HWSZ) % 16;
    int b  = idx / (HWSZ * 16);

    const float* kb = kern + (size_t)(b * 9) * HWSZ + h * WW + w;
    float kv[9];
#pragma unroll
    for (int t = 0; t < 9; ++t) kv[t] = kb[(size_t)t * HWSZ];

    const float* xb = x + (size_t)(b * CC + cg * 8) * HWSZ;
    float s[8] = {0.f, 0.f, 0.f, 0.f, 0.f, 0.f, 0.f, 0.f};
    int t = 0;
#pragma unroll
    for (int dy = 0; dy < 3; ++dy) {
#pragma unroll
        for (int dx = 0; dx < 3; ++dx) {
            int hh = h + dy - 1, ww2 = w + dx - 1;
            if ((unsigned)hh < (unsigned)HH && (unsigned)ww2 < (unsigned)WW) {
                const float* xp = xb + hh * WW + ww2;
#pragma unroll
                for (int j = 0; j < 8; ++j)
                    s[j] = fmaf(kv[t], xp[(size_t)j * HWSZ], s[j]);
            }
            ++t;
        }
    }
    short8 pk;
#pragma unroll
    for (int j = 0; j < 8; ++j) pk[j] = f2bf(s[j]);
    *(short8*)&t3[((((size_t)b * 16 + cg) * PD + h + 1) * PD + (w + 1)) * 8] = pk;
}

// ---------------------------------------------------------------------------
extern "C" void kernel_launch(void* const* d_in, const int* in_sizes, int n_in,
                              void* d_out, int out_size, void* d_ws, size_t ws_size,
                              hipStream_t stream) {
    const float* x   = (const float*)d_in[0];
    const float* w1  = (const float*)d_in[1];
    const float* b1  = (const float*)d_in[2];
    const float* w2  = (const float*)d_in[3];
    const float* b2  = (const float*)d_in[4];
    const float* w3  = (const float*)d_in[5];
    const float* b3  = (const float*)d_in[6];
    const float* f1  = (const float*)d_in[7];
    const float* fb1 = (const float*)d_in[8];
    const float* f2  = (const float*)d_in[9];
    const float* fb2 = (const float*)d_in[10];
    float* out = (float*)d_out;

    // workspace layout (bf16 activation buffers are padded 8c-blocked)
    const size_t ACT_SZ = (size_t)BB * 16 * PD * PD * 8;   // shorts, 128ch buffer
    short* xpad    = (short*)d_ws;
    short* regionA = xpad + ACT_SZ;       // t1 (64ch) then t3 (128ch)
    short* regionB = regionA + ACT_SZ;    // t2 (32ch) then t4 (128ch)
    float* kern    = (float*)(regionB + ACT_SZ);           // (B,9,H,W) fp32
    short* wp1     = (short*)(kern + (size_t)BB * 9 * HWSZ);
    short* wp2     = wp1 + 9 * 4 * 64 * 32;
    short* wpf1    = wp2 + 9 * 2 * 32 * 32;
    short* wpf2    = wpf1 + 9 * 4 * 128 * 32;

    short* t1 = regionA;
    short* t2 = regionB;
    short* t3 = regionA;   // overwrites t1 (dead)
    short* t4 = regionB;   // overwrites t2 (dead)

    // border zeroing + x conversion + weight prep
    {
        int nz = 3 * 64 * 772;
        zero_pads_kernel<<<(nz + 255) / 256, 256, 0, stream>>>(xpad, regionA, regionB);
        int nx = BB * 16 * HWSZ;
        x_prep_kernel<<<(nx + 255) / 256, 256, 0, stream>>>(x, xpad);
        int n1 = 9 * 4 * 64 * 32, n2 = 9 * 2 * 32 * 32, nf = 9 * 4 * 128 * 32;
        prep_w_kernel<<<(n1 + 255) / 256, 256, 0, stream>>>(w1, wp1, 128, 64, 1, n1);
        prep_w_kernel<<<(n2 + 255) / 256, 256, 0, stream>>>(w2, wp2, 64, 32, 1, n2);
        prep_w_kernel<<<(nf + 255) / 256, 256, 0, stream>>>(f1, wpf1, 128, 64, 2, nf);
        prep_w_kernel<<<(nf + 255) / 256, 256, 0, stream>>>(f2, wpf2, 128, 64, 2, nf);
    }

    // conv1: 128 -> 64, relu. 6 waves, WM=2; LDS 2x12.3 KB
    conv3x3_wlds<128, 64, 1, 2, true, false>
        <<<dim3(HH, BB), 384, 0, stream>>>(xpad, wp1, b1, t1);
    // conv2: 64 -> 32, relu. 6 waves, WM=1; LDS 2x6.1 KB
    conv3x3_wlds<64, 32, 1, 1, true, false>
        <<<dim3(HH, BB), 384, 0, stream>>>(t1, wp2, b2, t2);
    // conv3 1x1 + softmax -> kern
    conv1x1_softmax_kernel<<<(NPIX + 255) / 256, 256, 0, stream>>>(t2, w3, b3, kern);
    // adaptive filter apply (exact fp32 x) -> bf16 t3
    {
        int nd = BB * 16 * HWSZ;
        deblur_kernel<<<(nd + 255) / 256, 256, 0, stream>>>(x, kern, t3);
    }
    // f1: 128 -> 2x64 cout-slices, relu
    conv3x3_wlds<128, 64, 2, 2, true, false>
        <<<dim3(HH * 2, BB), 384, 0, stream>>>(t3, wpf1, fb1, t4);
    // f2: 128 -> 2x64 cout-slices, no relu -> final fp32 output
    conv3x3_wlds<128, 64, 2, 2, false, true>
        <<<dim3(HH * 2, BB), 384, 0, stream>>>(t4, wpf2, fb2, out);
}

// Round 8
// 333.935 us; speedup vs baseline: 1.0452x; 1.0452x over previous
//
#include <hip/hip_runtime.h>
#include <math.h>

// Problem constants (B, C, H, W) = (4, 128, 192, 192)
#define BB 4
#define CC 128
#define HH 192
#define WW 192
#define HWSZ (HH * WW)          // 36864
#define NPIX (BB * HWSZ)        // 147456
#define PD 194                  // padded H/W for bf16 activation buffers

typedef __attribute__((ext_vector_type(8))) short short8;
typedef __attribute__((ext_vector_type(4))) short short4v;
typedef __attribute__((ext_vector_type(4))) float float4v;

// fp32 -> bf16, round-to-nearest-even
__device__ __forceinline__ short f2bf(float f) {
    unsigned u = __float_as_uint(f);
    u += 0x7FFF + ((u >> 16) & 1);
    return (short)(u >> 16);
}
__device__ __forceinline__ float bf2f(short s) {
    return __uint_as_float(((unsigned)(unsigned short)s) << 16);
}

// ---------------------------------------------------------------------------
// Weight prep: w[co][cin][ky][kx] fp32 ->
//   wp[sl][ck][tt][tap3][lg][co_blk][ci8] bf16
// (slice-major so each cout-slice block DMAs a contiguous region;
//  k-major within a stage -> conflict-free ds_read_b128)
// ---------------------------------------------------------------------------
__global__ void prep_w_kernel(const float* __restrict__ w,
                              short* __restrict__ wp,
                              int CIN, int COUT, int NSLICE, int total) {
    int idx = blockIdx.x * blockDim.x + threadIdx.x;
    if (idx >= total) return;
    int CKN = CIN / 32;
    int ci8 = idx & 7;
    int t   = idx >> 3;
    int co  = t % COUT;  t /= COUT;
    int lg  = t % 4;     t /= 4;
    int tap3 = t % 3;    t /= 3;
    int tt  = t % 3;     t /= 3;
    int ck  = t % CKN;
    int sl  = t / CKN;
    int cin = ck * 32 + lg * 8 + ci8;
    int tap = tt * 3 + tap3;
    int co_g = sl * COUT + co;
    wp[idx] = f2bf(w[(co_g * CIN + cin) * 9 + tap]);
}

// ---------------------------------------------------------------------------
// Zero the borders of the three padded bf16 activation buffers.
// ---------------------------------------------------------------------------
__global__ void zero_pads_kernel(short* __restrict__ p0,
                                 short* __restrict__ p1,
                                 short* __restrict__ p2) {
    int idx = blockIdx.x * blockDim.x + threadIdx.x;
    if (idx >= 3 * 64 * 772) return;
    int e   = idx % 772;
    int bc  = (idx / 772) % 64;
    int buf = idx / (772 * 64);
    short* base = (buf == 0) ? p0 : (buf == 1) ? p1 : p2;
    int row, col;
    if (e < 194)      { row = 0;   col = e; }
    else if (e < 388) { row = 193; col = e - 194; }
    else { int e2 = e - 388; row = 1 + (e2 >> 1); col = (e2 & 1) * 193; }
    short8 z = {0, 0, 0, 0, 0, 0, 0, 0};
    *(short8*)&base[(((size_t)bc * PD + row) * PD + col) * 8] = z;
}

// ---------------------------------------------------------------------------
// x fp32 NCHW -> padded bf16 8c-blocked [b][cg][h+1][w+1][8]
// ---------------------------------------------------------------------------
__global__ void x_prep_kernel(const float* __restrict__ x,
                              short* __restrict__ xp) {
    int idx = blockIdx.x * blockDim.x + threadIdx.x;
    if (idx >= BB * 16 * HWSZ) return;
    int w  = idx % WW;
    int h  = (idx / WW) % HH;
    int cg = (idx / HWSZ) % 16;
    int b  = idx / (HWSZ * 16);
    const float* p = x + ((size_t)(b * CC + cg * 8) * HH + h) * WW + w;
    short8 pk;
#pragma unroll
    for (int j = 0; j < 8; ++j) pk[j] = f2bf(p[(size_t)j * HWSZ]);
    *(short8*)&xp[((((size_t)b * 16 + cg) * PD + h + 1) * PD + (w + 1)) * 8] = pk;
}

// ---------------------------------------------------------------------------
// Implicit-GEMM 3x3 conv, bf16 MFMA 16x16x32, fp32 accumulate.
// (R4-verified best configuration: 54.8us on f1/f2.)
// COUT split into NSLICE slices (independent 4-wave barrier domains).
// A (weights): 3-tap sub-chunks double-buffered via global_load_lds; rolling
//   2-deep A-fragment buffer. Counted vmcnt(9) at stage boundaries drains
//   only the staging DMAs; B prefetches stay in flight (T4).
// B (activations): per-lane row-base pointers + immediate offsets; ring-3,
//   distance-2 prefetch. T5 setprio around the MFMA cluster.
// Block -> (b,h,sl) chunked XCD swizzle for L2 row reuse.
// ---------------------------------------------------------------------------
template <int CIN, int COUT, int NSLICE, int WAVES_M, int WAVES_N, int WM, int WN,
          bool RELU, bool OUT_F32>
__global__ __launch_bounds__(WAVES_M * WAVES_N * 64, 4)
void conv3x3_wlds(const short* __restrict__ in,
                  const short* __restrict__ wp,   // [sl][stage][tap3][lg][co][8]
                  const float* __restrict__ bias,
                  void* __restrict__ outv) {
    constexpr int CKN   = CIN / 32;
    constexpr int CG_IN = CIN / 8;
    constexpr int COUT_TOT = COUT * NSLICE;
    constexpr int CGO   = COUT_TOT / 8;
    constexpr int NT    = WAVES_M * WAVES_N * 64;
    constexpr int SUB   = 3 * 4 * COUT * 8;      // shorts per 3-tap sub-chunk
    constexpr int SUBB  = SUB * 2;               // bytes
    constexpr int ATS   = 4 * COUT * 16;         // bytes per tap3 slice in LDS
    constexpr int NS    = CKN * 3;               // number of stages
    constexpr int KTMAX = CKN * 9;
    constexpr int CKB   = PD * PD * 64;          // B row-base advance per ck (bytes)
    constexpr int WPSL  = NS * SUB;              // shorts per cout-slice of wp
    constexpr int NWG   = BB * HH * NSLICE;      // total workgroups
    static_assert(WAVES_M * WM * 16 == COUT, "M tiling");
    static_assert(WAVES_N * WN * 16 == 192, "N tiling");

    __shared__ __align__(16) short s_w[2 * SUB];

    const int tid  = threadIdx.x;
    // ---- chunked XCD swizzle over (b, h, sl) work ids ----
    const int lin  = blockIdx.y * (HH * NSLICE) + blockIdx.x;
    const int L    = (lin & 7) * (NWG >> 3) + (lin >> 3);
    const int sl   = L % NSLICE;
    const int h    = (L / NSLICE) % HH;
    const int b    = L / (NSLICE * HH);
    const int lane = tid & 63;
    const int wv   = tid >> 6;
    const int wv_m = wv % WAVES_M;
    const int wv_n = wv / WAVES_M;
    const int ln15 = lane & 15;
    const int lg   = lane >> 4;              // k-subgroup 0..3 (8 cins each)

    float4v acc[WM][WN];
#pragma unroll
    for (int mi = 0; mi < WM; ++mi)
#pragma unroll
        for (int ni = 0; ni < WN; ++ni)
            acc[mi][ni] = (float4v){0.f, 0.f, 0.f, 0.f};

    short8 Aa[2][WM], Bb[3][WN];

    // ---- B row-base pointers, per-lane, column byte offset folded in ----
    const int colb = (wv_n * WN * 16 + ln15) * 16;
    const char* rowb0 = (const char*)(in +
        (((size_t)b * CG_IN + lg) * PD + h) * (size_t)PD * 8) + colb;
    const char* rowb1 = rowb0 + PD * 16;
    const char* rowb2 = rowb0 + 2 * PD * 16;

    // ---- A LDS base (per-lane); par/t3/mi become immediates ----
    const char* aBase = (const char*)&s_w[0] +
        lg * (COUT * 16) + (wv_m * WM) * 256 + ln15 * 16;

    // B load: dy/dx compile-time after unroll -> pure immediate-offset loads
    auto loadBpf = [&](int dy, int dx, short8* dst) {
        const char* rp = (dy == 0) ? rowb0 : (dy == 1) ? rowb1 : rowb2;
#pragma unroll
        for (int ni = 0; ni < WN; ++ni)
            dst[ni] = *(const short8*)(rp + dx * 16 + ni * 256);
    };

    // weight staging DMA (pure width-16), advances source/parity
    const short* wsrc = wp + (size_t)sl * WPSL;
    int wpar = 0;
    auto stageIssue = [&]() {
        constexpr int UNITS = SUB / 8;               // 16B units
        short* dstb = &s_w[wpar * SUB];
#pragma unroll
        for (int u = 0; u < (UNITS + NT - 1) / NT; ++u) {
            int i = tid + u * NT;
            if (UNITS % NT == 0 || i < UNITS)
                __builtin_amdgcn_global_load_lds(
                    (const __attribute__((address_space(1))) void*)&wsrc[i * 8],
                    (__attribute__((address_space(3))) void*)&dstb[i * 8], 16, 0, 0);
        }
        // pin later VMEM ops after the DMA issue (vmcnt count depends on it)
        asm volatile("" ::: "memory");
        wsrc += SUB;
        wpar ^= 1;
    };

    // ---- prologue: stage 0 weights, fill 2 B ring slots (taps 0,1) ----
    stageIssue();
    loadBpf(0, 0, Bb[0]);
    loadBpf(0, 1, Bb[1]);
    // outstanding: {<=3 DMA (oldest), 2*WN B} -> vmcnt(6) drains exactly the DMAs
    asm volatile("s_waitcnt vmcnt(6)" ::: "memory");
    __builtin_amdgcn_s_barrier();
    asm volatile("" ::: "memory");

    int par = 0;
    for (int ck = 0; ck < CKN; ++ck) {
#pragma unroll
        for (int tt = 0; tt < 3; ++tt) {
            const int s = ck * 3 + tt;
            const bool notLast = (s + 1 < NS);
            if (notLast) stageIssue();
            const char* aP = aBase + (par ? SUBB : 0);
            // A tap0 of this stage
#pragma unroll
            for (int mi = 0; mi < WM; ++mi)
                Aa[0][mi] = *(const short8*)(aP + mi * 256);
#pragma unroll
            for (int t3 = 0; t3 < 3; ++t3) {
                if (t3 < 2) {
#pragma unroll
                    for (int mi = 0; mi < WM; ++mi)
                        Aa[(t3 + 1) & 1][mi] =
                            *(const short8*)(aP + (t3 + 1) * ATS + mi * 256);
                }
                const int kt = s * 3 + t3;
                if (kt + 2 < KTMAX) {
                    const int tp = (tt * 3 + t3 + 2) % 9;   // compile-time
                    loadBpf(tp / 3, tp % 3, Bb[(t3 + 2) % 3]);
                }
                __builtin_amdgcn_s_setprio(1);
#pragma unroll
                for (int mi = 0; mi < WM; ++mi)
#pragma unroll
                    for (int ni = 0; ni < WN; ++ni)
                        acc[mi][ni] = __builtin_amdgcn_mfma_f32_16x16x32_bf16(
                            Aa[t3 & 1][mi], Bb[t3][ni], acc[mi][ni], 0, 0, 0);
                __builtin_amdgcn_s_setprio(0);
                // advance B row bases to next ck AFTER tap8 prefetch (tt=2,t3=0),
                // BEFORE the cross-ck prefetches at (2,1)/(2,2)
                if (tt == 2 && t3 == 0) {
                    rowb0 += CKB; rowb1 += CKB; rowb2 += CKB;
                }
            }
            if (notLast) {
                // outstanding: {DMA(s+1) oldest, <=9 B newest} -> drain DMAs only
                asm volatile("s_waitcnt vmcnt(9)" ::: "memory");
                __builtin_amdgcn_s_barrier();
                asm volatile("" ::: "memory");
                par ^= 1;
            }
        }
    }

    // ---- epilogue: C layout col=lane&15 (pixel), row=lg*4+reg (cout) ----
    if (OUT_F32) {
        float* out = (float*)outv;
#pragma unroll
        for (int mi = 0; mi < WM; ++mi) {
            int co0 = sl * COUT + (wv_m * WM + mi) * 16 + lg * 4;
#pragma unroll
            for (int r = 0; r < 4; ++r) {
                int co = co0 + r;
                float bv = bias[co];
#pragma unroll
                for (int ni = 0; ni < WN; ++ni) {
                    int wcol = (wv_n * WN + ni) * 16 + ln15;
                    float v = acc[mi][ni][r] + bv;
                    if (RELU) v = fmaxf(v, 0.f);
                    out[((size_t)(b * COUT_TOT + co) * HH + h) * WW + wcol] = v;
                }
            }
        }
    } else {
        short* out = (short*)outv;
#pragma unroll
        for (int mi = 0; mi < WM; ++mi) {
            int co0 = sl * COUT + (wv_m * WM + mi) * 16 + lg * 4;
            int cg  = co0 >> 3;
            int sub = co0 & 7;                           // 0 or 4
#pragma unroll
            for (int ni = 0; ni < WN; ++ni) {
                int wcol = (wv_n * WN + ni) * 16 + ln15;
                short4v pk;
#pragma unroll
                for (int r = 0; r < 4; ++r) {
                    float v = acc[mi][ni][r] + bias[co0 + r];
                    if (RELU) v = fmaxf(v, 0.f);
                    pk[r] = f2bf(v);
                }
                *(short4v*)&out[((((size_t)b * CGO + cg) * PD + (h + 1)) * PD +
                                 (wcol + 1)) * 8 + sub] = pk;
            }
        }
    }
}

// ---------------------------------------------------------------------------
// Fused conv1x1(32->9) + softmax + adaptive 3x3 filter apply.
// kern (B,9,H,W) is never materialized: each thread computes the 9 softmax
// weights in-register from t2 (identical fp32 math) and applies them to 4
// channel-groups of exact fp32 x, writing bf16 8c-blocked t3.
// Thread mapping: qc = idx / NPIX (outer) so w stays lane-contiguous ->
// all t2/x accesses remain coalesced.
// ---------------------------------------------------------------------------
__global__ void softmax_deblur_kernel(const short* __restrict__ t2,
                                      const float* __restrict__ w3,   // (9,32)
                                      const float* __restrict__ b3,
                                      const float* __restrict__ x,
                                      short* __restrict__ t3) {
    __shared__ float sw[9 * 32];
    __shared__ float sb[9];
    for (int i = threadIdx.x; i < 9 * 32; i += blockDim.x) sw[i] = w3[i];
    if (threadIdx.x < 9) sb[threadIdx.x] = b3[threadIdx.x];
    __syncthreads();

    int idx = blockIdx.x * blockDim.x + threadIdx.x;
    if (idx >= 4 * NPIX) return;
    int qc  = idx / NPIX;          // 4-cg group 0..3 (cgs qc*4 .. qc*4+3)
    int pid = idx % NPIX;
    int b = pid / HWSZ;
    int p = pid % HWSZ;
    int h = p / WW, w = p % WW;

    // conv1x1 logits + softmax -> kv[9]
    float v[32];
#pragma unroll
    for (int cg = 0; cg < 4; ++cg) {
        short8 pk = *(const short8*)
            &t2[((((size_t)b * 4 + cg) * PD + h + 1) * PD + (w + 1)) * 8];
#pragma unroll
        for (int j = 0; j < 8; ++j) v[cg * 8 + j] = bf2f(pk[j]);
    }
    float kv[9];
    float m = -1e30f;
#pragma unroll
    for (int t = 0; t < 9; ++t) {
        float s = sb[t];
#pragma unroll
        for (int c = 0; c < 32; ++c) s = fmaf(sw[t * 32 + c], v[c], s);
        kv[t] = s;
        m = fmaxf(m, s);
    }
    float sum = 0.f;
#pragma unroll
    for (int t = 0; t < 9; ++t) {
        kv[t] = __expf(kv[t] - m);
        sum += kv[t];
    }
    float inv = 1.f / sum;
#pragma unroll
    for (int t = 0; t < 9; ++t) kv[t] *= inv;

    // adaptive filter on 4 channel-groups (32 channels), exact fp32 x
#pragma unroll
    for (int cgo = 0; cgo < 4; ++cgo) {
        int cg = qc * 4 + cgo;
        const float* xb = x + (size_t)(b * CC + cg * 8) * HWSZ;
        float s[8] = {0.f, 0.f, 0.f, 0.f, 0.f, 0.f, 0.f, 0.f};
        int t = 0;
#pragma unroll
        for (int dy = 0; dy < 3; ++dy) {
#pragma unroll
            for (int dx = 0; dx < 3; ++dx) {
                int hh = h + dy - 1, ww2 = w + dx - 1;
                if ((unsigned)hh < (unsigned)HH && (unsigned)ww2 < (unsigned)WW) {
                    const float* xp = xb + hh * WW + ww2;
#pragma unroll
                    for (int j = 0; j < 8; ++j)
                        s[j] = fmaf(kv[t], xp[(size_t)j * HWSZ], s[j]);
                }
                ++t;
            }
        }
        short8 pk;
#pragma unroll
        for (int j = 0; j < 8; ++j) pk[j] = f2bf(s[j]);
        *(short8*)&t3[((((size_t)b * 16 + cg) * PD + h + 1) * PD + (w + 1)) * 8] = pk;
    }
}

// ---------------------------------------------------------------------------
extern "C" void kernel_launch(void* const* d_in, const int* in_sizes, int n_in,
                              void* d_out, int out_size, void* d_ws, size_t ws_size,
                              hipStream_t stream) {
    const float* x   = (const float*)d_in[0];
    const float* w1  = (const float*)d_in[1];
    const float* b1  = (const float*)d_in[2];
    const float* w2  = (const float*)d_in[3];
    const float* b2  = (const float*)d_in[4];
    const float* w3  = (const float*)d_in[5];
    const float* b3  = (const float*)d_in[6];
    const float* f1  = (const float*)d_in[7];
    const float* fb1 = (const float*)d_in[8];
    const float* f2  = (const float*)d_in[9];
    const float* fb2 = (const float*)d_in[10];
    float* out = (float*)d_out;

    // workspace layout (bf16 activation buffers are padded 8c-blocked)
    const size_t ACT_SZ = (size_t)BB * 16 * PD * PD * 8;   // shorts, 128ch buffer
    short* xpad    = (short*)d_ws;
    short* regionA = xpad + ACT_SZ;       // t1 (64ch) then t3 (128ch)
    short* regionB = regionA + ACT_SZ;    // t2 (32ch) then t4 (128ch)
    float* kern    = (float*)(regionB + ACT_SZ);           // (reserved, unused)
    short* wp1     = (short*)(kern + (size_t)BB * 9 * HWSZ);
    short* wp2     = wp1 + 9 * 4 * 64 * 32;
    short* wpf1    = wp2 + 9 * 2 * 32 * 32;
    short* wpf2    = wpf1 + 9 * 4 * 128 * 32;

    short* t1 = regionA;
    short* t2 = regionB;
    short* t3 = regionA;   // overwrites t1 (dead)
    short* t4 = regionB;   // overwrites t2 (dead)

    // border zeroing + x conversion + weight prep
    {
        int nz = 3 * 64 * 772;
        zero_pads_kernel<<<(nz + 255) / 256, 256, 0, stream>>>(xpad, regionA, regionB);
        int nx = BB * 16 * HWSZ;
        x_prep_kernel<<<(nx + 255) / 256, 256, 0, stream>>>(x, xpad);
        int n1 = 9 * 4 * 64 * 32, n2 = 9 * 2 * 32 * 32, nf = 9 * 4 * 128 * 32;
        prep_w_kernel<<<(n1 + 255) / 256, 256, 0, stream>>>(w1, wp1, 128, 32, 2, n1);
        prep_w_kernel<<<(n2 + 255) / 256, 256, 0, stream>>>(w2, wp2, 64, 32, 1, n2);
        prep_w_kernel<<<(nf + 255) / 256, 256, 0, stream>>>(f1, wpf1, 128, 64, 2, nf);
        prep_w_kernel<<<(nf + 255) / 256, 256, 0, stream>>>(f2, wpf2, 128, 64, 2, nf);
    }

    // conv1: 128 -> 2x32 cout-slices, relu. 4 waves, WM=2; LDS 2x6.1 KB
    conv3x3_wlds<128, 32, 2, 1, 4, 2, 3, true, false>
        <<<dim3(HH * 2, BB), 256, 0, stream>>>(xpad, wp1, b1, t1);
    // conv2: 64 -> 32, relu. 4 waves, WM=2; LDS 2x6.1 KB
    conv3x3_wlds<64, 32, 1, 1, 4, 2, 3, true, false>
        <<<dim3(HH, BB), 256, 0, stream>>>(t1, wp2, b2, t2);
    // fused conv1x1 + softmax + adaptive filter apply -> bf16 t3
    softmax_deblur_kernel<<<(4 * NPIX + 255) / 256, 256, 0, stream>>>(
        t2, w3, b3, x, t3);
    // f1: 128 -> 2x64 cout-slices, relu. 256-thr blocks (R4-verified best)
    conv3x3_wlds<128, 64, 2, 1, 4, 4, 3, true, false>
        <<<dim3(HH * 2, BB), 256, 0, stream>>>(t3, wpf1, fb1, t4);
    // f2: 128 -> 2x64 cout-slices, no relu -> final fp32 output
    conv3x3_wlds<128, 64, 2, 1, 4, 4, 3, false, true>
        <<<dim3(HH * 2, BB), 256, 0, stream>>>(t4, wpf2, fb2, out);
}

// Round 9
// 320.291 us; speedup vs baseline: 1.0897x; 1.0426x over previous
//
#include <hip/hip_runtime.h>
#include <math.h>

// Problem constants (B, C, H, W) = (4, 128, 192, 192)
#define BB 4
#define CC 128
#define HH 192
#define WW 192
#define HWSZ (HH * WW)          // 36864
#define NPIX (BB * HWSZ)        // 147456
#define PD 194                  // padded H/W for bf16 activation buffers

typedef __attribute__((ext_vector_type(8))) short short8;
typedef __attribute__((ext_vector_type(4))) short short4v;
typedef __attribute__((ext_vector_type(4))) float float4v;

// fp32 -> bf16, round-to-nearest-even
__device__ __forceinline__ short f2bf(float f) {
    unsigned u = __float_as_uint(f);
    u += 0x7FFF + ((u >> 16) & 1);
    return (short)(u >> 16);
}
__device__ __forceinline__ float bf2f(short s) {
    return __uint_as_float(((unsigned)(unsigned short)s) << 16);
}

// ---------------------------------------------------------------------------
// Weight prep: w[co][cin][ky][kx] fp32 ->
//   wp[sl][ck][tt][tap3][lg][co_blk][ci8] bf16
// (slice-major so each cout-slice block DMAs a contiguous region;
//  k-major within a stage -> conflict-free ds_read_b128)
// ---------------------------------------------------------------------------
__global__ void prep_w_kernel(const float* __restrict__ w,
                              short* __restrict__ wp,
                              int CIN, int COUT, int NSLICE, int total) {
    int idx = blockIdx.x * blockDim.x + threadIdx.x;
    if (idx >= total) return;
    int CKN = CIN / 32;
    int ci8 = idx & 7;
    int t   = idx >> 3;
    int co  = t % COUT;  t /= COUT;
    int lg  = t % 4;     t /= 4;
    int tap3 = t % 3;    t /= 3;
    int tt  = t % 3;     t /= 3;
    int ck  = t % CKN;
    int sl  = t / CKN;
    int cin = ck * 32 + lg * 8 + ci8;
    int tap = tt * 3 + tap3;
    int co_g = sl * COUT + co;
    wp[idx] = f2bf(w[(co_g * CIN + cin) * 9 + tap]);
}

// ---------------------------------------------------------------------------
// Zero the borders of the three padded bf16 activation buffers.
// ---------------------------------------------------------------------------
__global__ void zero_pads_kernel(short* __restrict__ p0,
                                 short* __restrict__ p1,
                                 short* __restrict__ p2) {
    int idx = blockIdx.x * blockDim.x + threadIdx.x;
    if (idx >= 3 * 64 * 772) return;
    int e   = idx % 772;
    int bc  = (idx / 772) % 64;
    int buf = idx / (772 * 64);
    short* base = (buf == 0) ? p0 : (buf == 1) ? p1 : p2;
    int row, col;
    if (e < 194)      { row = 0;   col = e; }
    else if (e < 388) { row = 193; col = e - 194; }
    else { int e2 = e - 388; row = 1 + (e2 >> 1); col = (e2 & 1) * 193; }
    short8 z = {0, 0, 0, 0, 0, 0, 0, 0};
    *(short8*)&base[(((size_t)bc * PD + row) * PD + col) * 8] = z;
}

// ---------------------------------------------------------------------------
// x fp32 NCHW -> padded bf16 8c-blocked [b][cg][h+1][w+1][8]
// ---------------------------------------------------------------------------
__global__ void x_prep_kernel(const float* __restrict__ x,
                              short* __restrict__ xp) {
    int idx = blockIdx.x * blockDim.x + threadIdx.x;
    if (idx >= BB * 16 * HWSZ) return;
    int w  = idx % WW;
    int h  = (idx / WW) % HH;
    int cg = (idx / HWSZ) % 16;
    int b  = idx / (HWSZ * 16);
    const float* p = x + ((size_t)(b * CC + cg * 8) * HH + h) * WW + w;
    short8 pk;
#pragma unroll
    for (int j = 0; j < 8; ++j) pk[j] = f2bf(p[(size_t)j * HWSZ]);
    *(short8*)&xp[((((size_t)b * 16 + cg) * PD + h + 1) * PD + (w + 1)) * 8] = pk;
}

// ---------------------------------------------------------------------------
// Implicit-GEMM 3x3 conv, bf16 MFMA 16x16x32, fp32 accumulate.
// (R4-verified best configuration: 54.8us on f1/f2.)
// COUT split into NSLICE slices (independent 4-wave barrier domains).
// A (weights): 3-tap sub-chunks double-buffered via global_load_lds; rolling
//   2-deep A-fragment buffer. Counted vmcnt(9) at stage boundaries drains
//   only the staging DMAs; B prefetches stay in flight (T4).
// B (activations): per-lane row-base pointers + immediate offsets; ring-3,
//   distance-2 prefetch. T5 setprio around the MFMA cluster.
// Block -> (b,h,sl) chunked XCD swizzle for L2 row reuse.
// ---------------------------------------------------------------------------
template <int CIN, int COUT, int NSLICE, int WAVES_M, int WAVES_N, int WM, int WN,
          bool RELU, bool OUT_F32>
__global__ __launch_bounds__(WAVES_M * WAVES_N * 64, 4)
void conv3x3_wlds(const short* __restrict__ in,
                  const short* __restrict__ wp,   // [sl][stage][tap3][lg][co][8]
                  const float* __restrict__ bias,
                  void* __restrict__ outv) {
    constexpr int CKN   = CIN / 32;
    constexpr int CG_IN = CIN / 8;
    constexpr int COUT_TOT = COUT * NSLICE;
    constexpr int CGO   = COUT_TOT / 8;
    constexpr int NT    = WAVES_M * WAVES_N * 64;
    constexpr int SUB   = 3 * 4 * COUT * 8;      // shorts per 3-tap sub-chunk
    constexpr int SUBB  = SUB * 2;               // bytes
    constexpr int ATS   = 4 * COUT * 16;         // bytes per tap3 slice in LDS
    constexpr int NS    = CKN * 3;               // number of stages
    constexpr int KTMAX = CKN * 9;
    constexpr int CKB   = PD * PD * 64;          // B row-base advance per ck (bytes)
    constexpr int WPSL  = NS * SUB;              // shorts per cout-slice of wp
    constexpr int NWG   = BB * HH * NSLICE;      // total workgroups
    static_assert(WAVES_M * WM * 16 == COUT, "M tiling");
    static_assert(WAVES_N * WN * 16 == 192, "N tiling");

    __shared__ __align__(16) short s_w[2 * SUB];

    const int tid  = threadIdx.x;
    // ---- chunked XCD swizzle over (b, h, sl) work ids ----
    const int lin  = blockIdx.y * (HH * NSLICE) + blockIdx.x;
    const int L    = (lin & 7) * (NWG >> 3) + (lin >> 3);
    const int sl   = L % NSLICE;
    const int h    = (L / NSLICE) % HH;
    const int b    = L / (NSLICE * HH);
    const int lane = tid & 63;
    const int wv   = tid >> 6;
    const int wv_m = wv % WAVES_M;
    const int wv_n = wv / WAVES_M;
    const int ln15 = lane & 15;
    const int lg   = lane >> 4;              // k-subgroup 0..3 (8 cins each)

    float4v acc[WM][WN];
#pragma unroll
    for (int mi = 0; mi < WM; ++mi)
#pragma unroll
        for (int ni = 0; ni < WN; ++ni)
            acc[mi][ni] = (float4v){0.f, 0.f, 0.f, 0.f};

    short8 Aa[2][WM], Bb[3][WN];

    // ---- B row-base pointers, per-lane, column byte offset folded in ----
    const int colb = (wv_n * WN * 16 + ln15) * 16;
    const char* rowb0 = (const char*)(in +
        (((size_t)b * CG_IN + lg) * PD + h) * (size_t)PD * 8) + colb;
    const char* rowb1 = rowb0 + PD * 16;
    const char* rowb2 = rowb0 + 2 * PD * 16;

    // ---- A LDS base (per-lane); par/t3/mi become immediates ----
    const char* aBase = (const char*)&s_w[0] +
        lg * (COUT * 16) + (wv_m * WM) * 256 + ln15 * 16;

    // B load: dy/dx compile-time after unroll -> pure immediate-offset loads
    auto loadBpf = [&](int dy, int dx, short8* dst) {
        const char* rp = (dy == 0) ? rowb0 : (dy == 1) ? rowb1 : rowb2;
#pragma unroll
        for (int ni = 0; ni < WN; ++ni)
            dst[ni] = *(const short8*)(rp + dx * 16 + ni * 256);
    };

    // weight staging DMA (pure width-16), advances source/parity
    const short* wsrc = wp + (size_t)sl * WPSL;
    int wpar = 0;
    auto stageIssue = [&]() {
        constexpr int UNITS = SUB / 8;               // 16B units
        short* dstb = &s_w[wpar * SUB];
#pragma unroll
        for (int u = 0; u < (UNITS + NT - 1) / NT; ++u) {
            int i = tid + u * NT;
            if (UNITS % NT == 0 || i < UNITS)
                __builtin_amdgcn_global_load_lds(
                    (const __attribute__((address_space(1))) void*)&wsrc[i * 8],
                    (__attribute__((address_space(3))) void*)&dstb[i * 8], 16, 0, 0);
        }
        // pin later VMEM ops after the DMA issue (vmcnt count depends on it)
        asm volatile("" ::: "memory");
        wsrc += SUB;
        wpar ^= 1;
    };

    // ---- prologue: stage 0 weights, fill 2 B ring slots (taps 0,1) ----
    stageIssue();
    loadBpf(0, 0, Bb[0]);
    loadBpf(0, 1, Bb[1]);
    // outstanding: {<=3 DMA (oldest), 2*WN B} -> vmcnt(6) drains exactly the DMAs
    asm volatile("s_waitcnt vmcnt(6)" ::: "memory");
    __builtin_amdgcn_s_barrier();
    asm volatile("" ::: "memory");

    int par = 0;
    for (int ck = 0; ck < CKN; ++ck) {
#pragma unroll
        for (int tt = 0; tt < 3; ++tt) {
            const int s = ck * 3 + tt;
            const bool notLast = (s + 1 < NS);
            if (notLast) stageIssue();
            const char* aP = aBase + (par ? SUBB : 0);
            // A tap0 of this stage
#pragma unroll
            for (int mi = 0; mi < WM; ++mi)
                Aa[0][mi] = *(const short8*)(aP + mi * 256);
#pragma unroll
            for (int t3 = 0; t3 < 3; ++t3) {
                if (t3 < 2) {
#pragma unroll
                    for (int mi = 0; mi < WM; ++mi)
                        Aa[(t3 + 1) & 1][mi] =
                            *(const short8*)(aP + (t3 + 1) * ATS + mi * 256);
                }
                const int kt = s * 3 + t3;
                if (kt + 2 < KTMAX) {
                    const int tp = (tt * 3 + t3 + 2) % 9;   // compile-time
                    loadBpf(tp / 3, tp % 3, Bb[(t3 + 2) % 3]);
                }
                __builtin_amdgcn_s_setprio(1);
#pragma unroll
                for (int mi = 0; mi < WM; ++mi)
#pragma unroll
                    for (int ni = 0; ni < WN; ++ni)
                        acc[mi][ni] = __builtin_amdgcn_mfma_f32_16x16x32_bf16(
                            Aa[t3 & 1][mi], Bb[t3][ni], acc[mi][ni], 0, 0, 0);
                __builtin_amdgcn_s_setprio(0);
                // advance B row bases to next ck AFTER tap8 prefetch (tt=2,t3=0),
                // BEFORE the cross-ck prefetches at (2,1)/(2,2)
                if (tt == 2 && t3 == 0) {
                    rowb0 += CKB; rowb1 += CKB; rowb2 += CKB;
                }
            }
            if (notLast) {
                // outstanding: {DMA(s+1) oldest, <=9 B newest} -> drain DMAs only
                asm volatile("s_waitcnt vmcnt(9)" ::: "memory");
                __builtin_amdgcn_s_barrier();
                asm volatile("" ::: "memory");
                par ^= 1;
            }
        }
    }

    // ---- epilogue: C layout col=lane&15 (pixel), row=lg*4+reg (cout) ----
    if (OUT_F32) {
        float* out = (float*)outv;
#pragma unroll
        for (int mi = 0; mi < WM; ++mi) {
            int co0 = sl * COUT + (wv_m * WM + mi) * 16 + lg * 4;
#pragma unroll
            for (int r = 0; r < 4; ++r) {
                int co = co0 + r;
                float bv = bias[co];
#pragma unroll
                for (int ni = 0; ni < WN; ++ni) {
                    int wcol = (wv_n * WN + ni) * 16 + ln15;
                    float v = acc[mi][ni][r] + bv;
                    if (RELU) v = fmaxf(v, 0.f);
                    out[((size_t)(b * COUT_TOT + co) * HH + h) * WW + wcol] = v;
                }
            }
        }
    } else {
        short* out = (short*)outv;
#pragma unroll
        for (int mi = 0; mi < WM; ++mi) {
            int co0 = sl * COUT + (wv_m * WM + mi) * 16 + lg * 4;
            int cg  = co0 >> 3;
            int sub = co0 & 7;                           // 0 or 4
#pragma unroll
            for (int ni = 0; ni < WN; ++ni) {
                int wcol = (wv_n * WN + ni) * 16 + ln15;
                short4v pk;
#pragma unroll
                for (int r = 0; r < 4; ++r) {
                    float v = acc[mi][ni][r] + bias[co0 + r];
                    if (RELU) v = fmaxf(v, 0.f);
                    pk[r] = f2bf(v);
                }
                *(short4v*)&out[((((size_t)b * CGO + cg) * PD + (h + 1)) * PD +
                                 (wcol + 1)) * 8 + sub] = pk;
            }
        }
    }
}

// ---------------------------------------------------------------------------
// Fused conv1x1(32->9) + softmax + adaptive 3x3 filter apply.
// kern (B,9,H,W) is never materialized. Patches now come from the bf16
// 8c-blocked xpad: one 16B load per (tap, cg) instead of 8 strided 4B fp32
// loads -> HBM read drops 75.5MB -> 19.3MB and the tap loop is branchless
// (pad border is pre-zeroed).
// ---------------------------------------------------------------------------
__global__ void softmax_deblur_kernel(const short* __restrict__ t2,
                                      const float* __restrict__ w3,   // (9,32)
                                      const float* __restrict__ b3,
                                      const short* __restrict__ xp,   // bf16 xpad
                                      short* __restrict__ t3) {
    __shared__ float sw[9 * 32];
    __shared__ float sb[9];
    for (int i = threadIdx.x; i < 9 * 32; i += blockDim.x) sw[i] = w3[i];
    if (threadIdx.x < 9) sb[threadIdx.x] = b3[threadIdx.x];
    __syncthreads();

    int idx = blockIdx.x * blockDim.x + threadIdx.x;
    if (idx >= 4 * NPIX) return;
    int qc  = idx / NPIX;          // 4-cg group 0..3 (cgs qc*4 .. qc*4+3)
    int pid = idx % NPIX;
    int b = pid / HWSZ;
    int p = pid % HWSZ;
    int h = p / WW, w = p % WW;

    // conv1x1 logits + softmax -> kv[9]
    float v[32];
#pragma unroll
    for (int cg = 0; cg < 4; ++cg) {
        short8 pk = *(const short8*)
            &t2[((((size_t)b * 4 + cg) * PD + h + 1) * PD + (w + 1)) * 8];
#pragma unroll
        for (int j = 0; j < 8; ++j) v[cg * 8 + j] = bf2f(pk[j]);
    }
    float kv[9];
    float m = -1e30f;
#pragma unroll
    for (int t = 0; t < 9; ++t) {
        float s = sb[t];
#pragma unroll
        for (int c = 0; c < 32; ++c) s = fmaf(sw[t * 32 + c], v[c], s);
        kv[t] = s;
        m = fmaxf(m, s);
    }
    float sum = 0.f;
#pragma unroll
    for (int t = 0; t < 9; ++t) {
        kv[t] = __expf(kv[t] - m);
        sum += kv[t];
    }
    float inv = 1.f / sum;
#pragma unroll
    for (int t = 0; t < 9; ++t) kv[t] *= inv;

    // adaptive filter on 4 channel-groups (32 channels) from bf16 xpad.
    // patch (dy,dx) of pixel (h,w) sits at padded (h+dy, w+dx); border rows/
    // cols are pre-zeroed -> branchless.
#pragma unroll
    for (int cgo = 0; cgo < 4; ++cgo) {
        int cg = qc * 4 + cgo;
        const short* xb = &xp[(((size_t)(b * 16 + cg) * PD + h) * PD + w) * 8];
        float s[8] = {0.f, 0.f, 0.f, 0.f, 0.f, 0.f, 0.f, 0.f};
        int t = 0;
#pragma unroll
        for (int dy = 0; dy < 3; ++dy) {
#pragma unroll
            for (int dx = 0; dx < 3; ++dx) {
                short8 px = *(const short8*)&xb[((size_t)dy * PD + dx) * 8];
#pragma unroll
                for (int j = 0; j < 8; ++j)
                    s[j] = fmaf(kv[t], bf2f(px[j]), s[j]);
                ++t;
            }
        }
        short8 pk;
#pragma unroll
        for (int j = 0; j < 8; ++j) pk[j] = f2bf(s[j]);
        *(short8*)&t3[((((size_t)b * 16 + cg) * PD + h + 1) * PD + (w + 1)) * 8] = pk;
    }
}

// ---------------------------------------------------------------------------
extern "C" void kernel_launch(void* const* d_in, const int* in_sizes, int n_in,
                              void* d_out, int out_size, void* d_ws, size_t ws_size,
                              hipStream_t stream) {
    const float* x   = (const float*)d_in[0];
    const float* w1  = (const float*)d_in[1];
    const float* b1  = (const float*)d_in[2];
    const float* w2  = (const float*)d_in[3];
    const float* b2  = (const float*)d_in[4];
    const float* w3  = (const float*)d_in[5];
    const float* b3  = (const float*)d_in[6];
    const float* f1  = (const float*)d_in[7];
    const float* fb1 = (const float*)d_in[8];
    const float* f2  = (const float*)d_in[9];
    const float* fb2 = (const float*)d_in[10];
    float* out = (float*)d_out;

    // workspace layout (bf16 activation buffers are padded 8c-blocked)
    const size_t ACT_SZ = (size_t)BB * 16 * PD * PD * 8;   // shorts, 128ch buffer
    short* xpad    = (short*)d_ws;
    short* regionA = xpad + ACT_SZ;       // t1 (64ch) then t3 (128ch)
    short* regionB = regionA + ACT_SZ;    // t2 (32ch) then t4 (128ch)
    float* kern    = (float*)(regionB + ACT_SZ);           // (reserved, unused)
    short* wp1     = (short*)(kern + (size_t)BB * 9 * HWSZ);
    short* wp2     = wp1 + 9 * 4 * 64 * 32;
    short* wpf1    = wp2 + 9 * 2 * 32 * 32;
    short* wpf2    = wpf1 + 9 * 4 * 128 * 32;

    short* t1 = regionA;
    short* t2 = regionB;
    short* t3 = regionA;   // overwrites t1 (dead)
    short* t4 = regionB;   // overwrites t2 (dead)

    // border zeroing + x conversion + weight prep
    {
        int nz = 3 * 64 * 772;
        zero_pads_kernel<<<(nz + 255) / 256, 256, 0, stream>>>(xpad, regionA, regionB);
        int nx = BB * 16 * HWSZ;
        x_prep_kernel<<<(nx + 255) / 256, 256, 0, stream>>>(x, xpad);
        int n1 = 9 * 4 * 64 * 32, n2 = 9 * 2 * 32 * 32, nf = 9 * 4 * 128 * 32;
        prep_w_kernel<<<(n1 + 255) / 256, 256, 0, stream>>>(w1, wp1, 128, 32, 2, n1);
        prep_w_kernel<<<(n2 + 255) / 256, 256, 0, stream>>>(w2, wp2, 64, 32, 1, n2);
        prep_w_kernel<<<(nf + 255) / 256, 256, 0, stream>>>(f1, wpf1, 128, 64, 2, nf);
        prep_w_kernel<<<(nf + 255) / 256, 256, 0, stream>>>(f2, wpf2, 128, 64, 2, nf);
    }

    // conv1: 128 -> 2x32 cout-slices, relu. 4 waves, WM=2; LDS 2x6.1 KB
    conv3x3_wlds<128, 32, 2, 1, 4, 2, 3, true, false>
        <<<dim3(HH * 2, BB), 256, 0, stream>>>(xpad, wp1, b1, t1);
    // conv2: 64 -> 32, relu. 4 waves, WM=2; LDS 2x6.1 KB
    conv3x3_wlds<64, 32, 1, 1, 4, 2, 3, true, false>
        <<<dim3(HH, BB), 256, 0, stream>>>(t1, wp2, b2, t2);
    // fused conv1x1 + softmax + adaptive filter apply (bf16 xpad) -> bf16 t3
    softmax_deblur_kernel<<<(4 * NPIX + 255) / 256, 256, 0, stream>>>(
        t2, w3, b3, xpad, t3);
    // f1: 128 -> 2x64 cout-slices, relu. 256-thr blocks (R4-verified best)
    conv3x3_wlds<128, 64, 2, 1, 4, 4, 3, true, false>
        <<<dim3(HH * 2, BB), 256, 0, stream>>>(t3, wpf1, fb1, t4);
    // f2: 128 -> 2x64 cout-slices, no relu -> final fp32 output
    conv3x3_wlds<128, 64, 2, 1, 4, 4, 3, false, true>
        <<<dim3(HH * 2, BB), 256, 0, stream>>>(t4, wpf2, fb2, out);
}